// Round 3
// baseline (1043.612 us; speedup 1.0000x reference)
//
#include <hip/hip_runtime.h>
#include <hip/hip_bf16.h>

#define DM 1024
#define NH 16
#define DH 64
#define DFF 4096
#define NBATCH 2
#define SEQL 2048
#define MTOK (NBATCH*SEQL)

typedef float f32x4 __attribute__((ext_vector_type(4)));
typedef __bf16 bf16x8 __attribute__((ext_vector_type(8)));
typedef unsigned short u16;
typedef unsigned int u32;
typedef unsigned short u16x4 __attribute__((ext_vector_type(4)));
typedef unsigned short u16x8 __attribute__((ext_vector_type(8)));
typedef unsigned int u32x4 __attribute__((ext_vector_type(4)));

__device__ __forceinline__ u16 f2bf(float f) {
    u32 u = __builtin_bit_cast(u32, f);
    return (u16)((u + 0x7fffu + ((u >> 16) & 1u)) >> 16);
}
__device__ __forceinline__ float bf2f(u16 h) {
    return __builtin_bit_cast(float, (u32)h << 16);
}
__device__ __forceinline__ f32x4 mfma16(bf16x8 a, bf16x8 b, f32x4 c) {
    return __builtin_amdgcn_mfma_f32_16x16x32_bf16(a, b, c, 0, 0, 0);
}

// ---------------------------------------------------------------------------
// Shared GEMM core: C[128x128] tile of A[M,K](bf16 hi/lo) @ W[N,K](f32)^T.
// 256 threads = 4 waves in 2x2; each wave owns a 64x64 sub-tile (4x4 frags of
// 16x16). BK=64. LDS XOR-swizzle: 16B chunk c stored at c^(row&7) -> frag
// ds_read_b128 spreads 16 lanes over 8 slots = conflict-free (2-way max).
// Split fp32 = bf16_hi + bf16_lo; product via 3 MFMAs (drop lo*lo ~ 2^-18).
// ---------------------------------------------------------------------------
__device__ __forceinline__ void gemm_core(
    const u16* __restrict__ Ah, const u16* __restrict__ Al,
    const float* __restrict__ W, int K, int m0, int n0,
    u16* lsAh, u16* lsAl, u16* lsBh, u16* lsBl,
    f32x4 acc[4][4])
{
    const int t = threadIdx.x;
    const int lane = t & 63;
    const int wm = ((t >> 7) & 1) * 64;
    const int wn = ((t >> 6) & 1) * 64;
    const int lrow = lane & 15;
    const int lk = lane >> 4;
    const f32x4 FZ = {0.f, 0.f, 0.f, 0.f};
#pragma unroll
    for (int i = 0; i < 4; ++i)
#pragma unroll
        for (int j = 0; j < 4; ++j) acc[i][j] = FZ;

    for (int k0 = 0; k0 < K; k0 += 64) {
        // stage A (already bf16 hi/lo): 128 rows x 64 cols
#pragma unroll
        for (int j = 0; j < 4; ++j) {
            const int row = (t >> 3) + j * 32;
            const int chk = t & 7;
            const size_t src = (size_t)(m0 + row) * K + k0 + chk * 8;
            const int di = row * 64 + ((chk ^ (row & 7)) << 3);
            *reinterpret_cast<u16x8*>(&lsAh[di]) = *reinterpret_cast<const u16x8*>(&Ah[src]);
            *reinterpret_cast<u16x8*>(&lsAl[di]) = *reinterpret_cast<const u16x8*>(&Al[src]);
        }
        // stage B: fp32 weights, split hi/lo on the fly
#pragma unroll
        for (int j = 0; j < 8; ++j) {
            const int id = t + j * 256;
            const int row = id >> 4;
            const int f4 = id & 15;
            const f32x4 wv = *reinterpret_cast<const f32x4*>(&W[(size_t)(n0 + row) * K + k0 + f4 * 4]);
            u16x4 hh, ll;
#pragma unroll
            for (int e = 0; e < 4; ++e) {
                const u16 hi = f2bf(wv[e]);
                hh[e] = hi;
                ll[e] = f2bf(wv[e] - bf2f(hi));
            }
            const int kc = f4 * 4;
            const int di = row * 64 + ((((kc >> 3) ^ (row & 7))) << 3) + (kc & 7);
            *reinterpret_cast<u16x4*>(&lsBh[di]) = hh;
            *reinterpret_cast<u16x4*>(&lsBl[di]) = ll;
        }
        __syncthreads();
#pragma unroll
        for (int ks = 0; ks < 2; ++ks) {
            bf16x8 ah[4], al[4], bh[4], bl[4];
#pragma unroll
            for (int i = 0; i < 4; ++i) {
                const int ra = wm + i * 16 + lrow;
                const int ia = ra * 64 + ((((lk + ks * 4) ^ (ra & 7))) << 3);
                ah[i] = *reinterpret_cast<const bf16x8*>(&lsAh[ia]);
                al[i] = *reinterpret_cast<const bf16x8*>(&lsAl[ia]);
                const int rb = wn + i * 16 + lrow;
                const int ib = rb * 64 + ((((lk + ks * 4) ^ (rb & 7))) << 3);
                bh[i] = *reinterpret_cast<const bf16x8*>(&lsBh[ib]);
                bl[i] = *reinterpret_cast<const bf16x8*>(&lsBl[ib]);
            }
#pragma unroll
            for (int i = 0; i < 4; ++i)
#pragma unroll
                for (int j = 0; j < 4; ++j) {
                    acc[i][j] = mfma16(ah[i], bh[j], acc[i][j]);
                    acc[i][j] = mfma16(al[i], bh[j], acc[i][j]);
                    acc[i][j] = mfma16(ah[i], bl[j], acc[i][j]);
                }
        }
        __syncthreads();
    }
}

// C/D frag mapping (HW-verified, guide m89): col = lane&15, row = (lane>>4)*4 + r
template <class F>
__device__ __forceinline__ void epilogue(const f32x4 acc[4][4], int m0, int n0, F f) {
    const int lane = threadIdx.x & 63;
    const int wm = ((threadIdx.x >> 7) & 1) * 64;
    const int wn = ((threadIdx.x >> 6) & 1) * 64;
#pragma unroll
    for (int i = 0; i < 4; ++i)
#pragma unroll
        for (int j = 0; j < 4; ++j)
#pragma unroll
            for (int r = 0; r < 4; ++r) {
                const int m = m0 + wm + i * 16 + ((lane >> 4) << 2) + r;
                const int o = n0 + wn + j * 16 + (lane & 15);
                f(m, o, acc[i][j][r]);
            }
}

// ---------------------------------------------------------------------------
__global__ __launch_bounds__(256) void k_rmsnorm(
    const float* __restrict__ x, const float* __restrict__ g,
    u16* __restrict__ oh, u16* __restrict__ ol)
{
    const int row = blockIdx.x * 4 + (threadIdx.x >> 6);
    const int lane = threadIdx.x & 63;
    const float* xr = x + (size_t)row * DM;
    f32x4 v[4];
    float ss = 0.f;
#pragma unroll
    for (int j = 0; j < 4; ++j) {
        v[j] = *reinterpret_cast<const f32x4*>(&xr[(lane + j * 64) * 4]);
        ss += v[j][0] * v[j][0] + v[j][1] * v[j][1] + v[j][2] * v[j][2] + v[j][3] * v[j][3];
    }
#pragma unroll
    for (int off = 32; off > 0; off >>= 1) ss += __shfl_xor(ss, off, 64);
    const float sc = 1.0f / sqrtf(ss * (1.0f / (float)DM) + 1e-5f);
#pragma unroll
    for (int j = 0; j < 4; ++j) {
        const int c0 = (lane + j * 64) * 4;
        const f32x4 gv = *reinterpret_cast<const f32x4*>(&g[c0]);
        u16x4 hh, ll;
#pragma unroll
        for (int e = 0; e < 4; ++e) {
            const float y = v[j][e] * sc * gv[e];
            const u16 hi = f2bf(y);
            hh[e] = hi;
            ll[e] = f2bf(y - bf2f(hi));
        }
        *reinterpret_cast<u16x4*>(&oh[(size_t)row * DM + c0]) = hh;
        *reinterpret_cast<u16x4*>(&ol[(size_t)row * DM + c0]) = ll;
    }
}

// QKV: grid (32, 24); y covers 3*1024 cols; writes q/k/v split in [B,H,S,dh]
__global__ __launch_bounds__(256) void k_qkv(
    const u16* __restrict__ Ah, const u16* __restrict__ Al,
    const float* __restrict__ Wq, const float* __restrict__ Wk, const float* __restrict__ Wv,
    u16* __restrict__ qh, u16* __restrict__ ql, u16* __restrict__ kh, u16* __restrict__ kl,
    u16* __restrict__ vh, u16* __restrict__ vl)
{
    __shared__ __align__(16) u16 lsAh[128 * 64], lsAl[128 * 64], lsBh[128 * 64], lsBl[128 * 64];
    const int m0 = blockIdx.x * 128;
    const int ng = blockIdx.y * 128;
    const int proj = ng >> 10;
    const int n0 = ng & 1023;
    const float* W = (proj == 0) ? Wq : ((proj == 1) ? Wk : Wv);
    u16* oph = (proj == 0) ? qh : ((proj == 1) ? kh : vh);
    u16* opl = (proj == 0) ? ql : ((proj == 1) ? kl : vl);
    f32x4 acc[4][4];
    gemm_core(Ah, Al, W, DM, m0, n0, lsAh, lsAl, lsBh, lsBl, acc);
    epilogue(acc, m0, n0, [&](int m, int o, float val) {
        const int b = m >> 11, s = m & (SEQL - 1);
        const int hd = o >> 6, d = o & 63;
        const size_t idx = (((size_t)b * NH + hd) * SEQL + s) * DH + d;
        const u16 hi = f2bf(val);
        oph[idx] = hi;
        opl[idx] = f2bf(val - bf2f(hi));
    });
}

// O-projection + residual: out = x + ao @ Wo^T ; grid (32, 8)
__global__ __launch_bounds__(256) void k_oproj(
    const u16* __restrict__ Ah, const u16* __restrict__ Al,
    const float* __restrict__ Wo, const float* __restrict__ xres, float* __restrict__ out)
{
    __shared__ __align__(16) u16 lsAh[128 * 64], lsAl[128 * 64], lsBh[128 * 64], lsBl[128 * 64];
    const int m0 = blockIdx.x * 128;
    const int n0 = blockIdx.y * 128;
    f32x4 acc[4][4];
    gemm_core(Ah, Al, Wo, DM, m0, n0, lsAh, lsAl, lsBh, lsBl, acc);
    epilogue(acc, m0, n0, [&](int m, int o, float val) {
        const size_t idx = (size_t)m * DM + o;
        out[idx] = xres[idx] + val;
    });
}

// FFN1: h1 = xn2 @ W1^T (split-stored to ws) ; grid (32, 32)
__global__ __launch_bounds__(256) void k_ffn1(
    const u16* __restrict__ Ah, const u16* __restrict__ Al,
    const float* __restrict__ W1, u16* __restrict__ hh, u16* __restrict__ hl)
{
    __shared__ __align__(16) u16 lsAh[128 * 64], lsAl[128 * 64], lsBh[128 * 64], lsBl[128 * 64];
    const int m0 = blockIdx.x * 128;
    const int n0 = blockIdx.y * 128;
    f32x4 acc[4][4];
    gemm_core(Ah, Al, W1, DM, m0, n0, lsAh, lsAl, lsBh, lsBl, acc);
    epilogue(acc, m0, n0, [&](int m, int o, float val) {
        const size_t idx = (size_t)m * DFF + o;
        const u16 hi = f2bf(val);
        hh[idx] = hi;
        hl[idx] = f2bf(val - bf2f(hi));
    });
}

// FFN3: h3 = xn2 @ W3^T; h = silu(h1)*h3 overwrites h (thread-local RMW, no race)
__global__ __launch_bounds__(256) void k_ffn3(
    const u16* __restrict__ Ah, const u16* __restrict__ Al,
    const float* __restrict__ W3, u16* __restrict__ hh, u16* __restrict__ hl)
{
    __shared__ __align__(16) u16 lsAh[128 * 64], lsAl[128 * 64], lsBh[128 * 64], lsBl[128 * 64];
    const int m0 = blockIdx.x * 128;
    const int n0 = blockIdx.y * 128;
    f32x4 acc[4][4];
    gemm_core(Ah, Al, W3, DM, m0, n0, lsAh, lsAl, lsBh, lsBl, acc);
    epilogue(acc, m0, n0, [&](int m, int o, float val) {
        const size_t idx = (size_t)m * DFF + o;
        const float h1 = bf2f(hh[idx]) + bf2f(hl[idx]);
        const float sg = 1.0f / (1.0f + expf(-h1));
        const float hv = h1 * sg * val;
        const u16 hi = f2bf(hv);
        hh[idx] = hi;
        hl[idx] = f2bf(hv - bf2f(hi));
    });
}

// FFN2 + residual: out += h @ W2^T ; grid (32, 8)
__global__ __launch_bounds__(256) void k_ffn2(
    const u16* __restrict__ Ah, const u16* __restrict__ Al,
    const float* __restrict__ W2, float* __restrict__ out)
{
    __shared__ __align__(16) u16 lsAh[128 * 64], lsAl[128 * 64], lsBh[128 * 64], lsBl[128 * 64];
    const int m0 = blockIdx.x * 128;
    const int n0 = blockIdx.y * 128;
    f32x4 acc[4][4];
    gemm_core(Ah, Al, W2, DFF, m0, n0, lsAh, lsAl, lsBh, lsBl, acc);
    epilogue(acc, m0, n0, [&](int m, int o, float val) {
        const size_t idx = (size_t)m * DM + o;
        out[idx] = out[idx] + val;
    });
}

// ---------------------------------------------------------------------------
// Flash attention, causal. grid (S/128, B*H), 256 threads = 4 waves; each wave
// owns 32 q-rows. KV tiles of 64. Q kept in registers; K and V^T staged in
// LDS (swizzled); P redistributed D-layout -> A-layout via packed u32 LDS.
// Split-bf16 on both QK^T and PV for fp32-class accuracy.
// ---------------------------------------------------------------------------
__global__ __launch_bounds__(256) void k_attn(
    const u16* __restrict__ gqh, const u16* __restrict__ gql,
    const u16* __restrict__ gkh, const u16* __restrict__ gkl,
    const u16* __restrict__ gvh, const u16* __restrict__ gvl,
    u16* __restrict__ aoh, u16* __restrict__ aol)
{
    __shared__ __align__(16) u16 Kh[64 * 64], Kl[64 * 64], Vth[64 * 64], Vtl[64 * 64];
    __shared__ __align__(16) u32 Pw[4][32 * 64];
    const int t = threadIdx.x, lane = t & 63, wid = t >> 6;
    const int lrow = lane & 15, lk = lane >> 4;
    const int bh = blockIdx.y;
    const int q0 = blockIdx.x * 128;
    const int qw = q0 + wid * 32;
    const size_t base = (size_t)bh * SEQL * DH;
    const f32x4 FZ = {0.f, 0.f, 0.f, 0.f};

    bf16x8 Qhf[2][2], Qlf[2][2];
#pragma unroll
    for (int mf = 0; mf < 2; ++mf)
#pragma unroll
        for (int ks = 0; ks < 2; ++ks) {
            const size_t off = base + (size_t)(qw + mf * 16 + lrow) * DH + lk * 8 + ks * 32;
            Qhf[mf][ks] = *reinterpret_cast<const bf16x8*>(&gqh[off]);
            Qlf[mf][ks] = *reinterpret_cast<const bf16x8*>(&gql[off]);
        }

    float mrun[2][4], lrun[2][4];
    f32x4 Oa[2][4];
#pragma unroll
    for (int mf = 0; mf < 2; ++mf)
#pragma unroll
        for (int r = 0; r < 4; ++r) { mrun[mf][r] = -1.0e30f; lrun[mf][r] = 0.f; }
#pragma unroll
    for (int mf = 0; mf < 2; ++mf)
#pragma unroll
        for (int n = 0; n < 4; ++n) Oa[mf][n] = FZ;

    const int ntile = (q0 + 128) >> 6;
    for (int it = 0; it < ntile; ++it) {
        const int kv0 = it << 6;
        // cooperative staging of K tile and transposed V tile
#pragma unroll
        for (int j = 0; j < 2; ++j) {
            const int id = t + j * 256;
            const int row = id >> 3, chk = id & 7;
            const size_t src = base + (size_t)(kv0 + row) * DH + chk * 8;
            const int di = row * 64 + ((chk ^ (row & 7)) << 3);
            *reinterpret_cast<u16x8*>(&Kh[di]) = *reinterpret_cast<const u16x8*>(&gkh[src]);
            *reinterpret_cast<u16x8*>(&Kl[di]) = *reinterpret_cast<const u16x8*>(&gkl[src]);
            const u16x8 vh8 = *reinterpret_cast<const u16x8*>(&gvh[src]);
            const u16x8 vl8 = *reinterpret_cast<const u16x8*>(&gvl[src]);
#pragma unroll
            for (int e = 0; e < 8; ++e) {
                const int dd = chk * 8 + e;
                const int dv = dd * 64 + ((((row >> 3) ^ (dd & 7))) << 3) + (row & 7);
                Vth[dv] = vh8[e];
                Vtl[dv] = vl8[e];
            }
        }
        __syncthreads();
        if (kv0 <= qw + 31) {  // skip fully-masked tiles for this wave
            f32x4 S[2][4];
#pragma unroll
            for (int mf = 0; mf < 2; ++mf)
#pragma unroll
                for (int nf = 0; nf < 4; ++nf) S[mf][nf] = FZ;
#pragma unroll
            for (int ks = 0; ks < 2; ++ks) {
                bf16x8 kbh[4], kbl[4];
#pragma unroll
                for (int nf = 0; nf < 4; ++nf) {
                    const int row = nf * 16 + lrow;
                    const int idx = row * 64 + (((lk + ks * 4) ^ (row & 7)) << 3);
                    kbh[nf] = *reinterpret_cast<const bf16x8*>(&Kh[idx]);
                    kbl[nf] = *reinterpret_cast<const bf16x8*>(&Kl[idx]);
                }
#pragma unroll
                for (int mf = 0; mf < 2; ++mf)
#pragma unroll
                    for (int nf = 0; nf < 4; ++nf) {
                        S[mf][nf] = mfma16(Qhf[mf][ks], kbh[nf], S[mf][nf]);
                        S[mf][nf] = mfma16(Qlf[mf][ks], kbh[nf], S[mf][nf]);
                        S[mf][nf] = mfma16(Qhf[mf][ks], kbl[nf], S[mf][nf]);
                    }
            }
            // online softmax (scale 1/8 after mask, matching reference)
#pragma unroll
            for (int mf = 0; mf < 2; ++mf)
#pragma unroll
                for (int r = 0; r < 4; ++r) {
                    const int qrow = qw + mf * 16 + (lk << 2) + r;
                    float rmx = -3.0e38f;
#pragma unroll
                    for (int nf = 0; nf < 4; ++nf) {
                        const int col = kv0 + nf * 16 + lrow;
                        const float tv = (col <= qrow) ? S[mf][nf][r] * 0.125f : -3.0e38f;
                        S[mf][nf][r] = tv;
                        rmx = fmaxf(rmx, tv);
                    }
#pragma unroll
                    for (int off = 8; off > 0; off >>= 1) rmx = fmaxf(rmx, __shfl_xor(rmx, off, 16));
                    const float mnew = fmaxf(mrun[mf][r], rmx);
                    const float alpha = exp2f((mrun[mf][r] - mnew) * 1.44269504f);
                    mrun[mf][r] = mnew;
                    float rsum = 0.f;
#pragma unroll
                    for (int nf = 0; nf < 4; ++nf) {
                        const float p = exp2f((S[mf][nf][r] - mnew) * 1.44269504f);
                        S[mf][nf][r] = p;
                        rsum += p;
                    }
#pragma unroll
                    for (int off = 8; off > 0; off >>= 1) rsum += __shfl_xor(rsum, off, 16);
                    lrun[mf][r] = lrun[mf][r] * alpha + rsum;
#pragma unroll
                    for (int n = 0; n < 4; ++n) Oa[mf][n][r] *= alpha;
                    const int prow = mf * 16 + (lk << 2) + r;
#pragma unroll
                    for (int nf = 0; nf < 4; ++nf) {
                        const float p = S[mf][nf][r];
                        const u16 phi = f2bf(p);
                        const u16 plo = f2bf(p - bf2f(phi));
                        const int pcol = nf * 16 + lrow;
                        Pw[wid][prow * 64 + ((((pcol >> 3) ^ (prow & 7))) << 3) + (pcol & 7)] =
                            (u32)phi | ((u32)plo << 16);
                    }
                }
            asm volatile("s_waitcnt lgkmcnt(0)" ::: "memory");
            // P (A-layout) @ V
#pragma unroll
            for (int ks = 0; ks < 2; ++ks) {
                bf16x8 pah[2], pal[2];
#pragma unroll
                for (int mf = 0; mf < 2; ++mf) {
                    const int row = mf * 16 + lrow;
                    const int c = (lk + ks * 4) ^ (row & 7);
                    const u32* pp = &Pw[wid][row * 64 + (c << 3)];
                    const u32x4 w0 = *reinterpret_cast<const u32x4*>(pp);
                    const u32x4 w1 = *reinterpret_cast<const u32x4*>(pp + 4);
                    union { u16 s[8]; bf16x8 v; } uh, ul;
#pragma unroll
                    for (int e = 0; e < 4; ++e) {
                        uh.s[e] = (u16)(w0[e] & 0xffffu); ul.s[e] = (u16)(w0[e] >> 16);
                        uh.s[e + 4] = (u16)(w1[e] & 0xffffu); ul.s[e + 4] = (u16)(w1[e] >> 16);
                    }
                    pah[mf] = uh.v; pal[mf] = ul.v;
                }
                bf16x8 vbh[4], vbl[4];
#pragma unroll
                for (int n = 0; n < 4; ++n) {
                    const int row = n * 16 + lrow;
                    const int idx = row * 64 + (((lk + ks * 4) ^ (row & 7)) << 3);
                    vbh[n] = *reinterpret_cast<const bf16x8*>(&Vth[idx]);
                    vbl[n] = *reinterpret_cast<const bf16x8*>(&Vtl[idx]);
                }
#pragma unroll
                for (int mf = 0; mf < 2; ++mf)
#pragma unroll
                    for (int n = 0; n < 4; ++n) {
                        Oa[mf][n] = mfma16(pah[mf], vbh[n], Oa[mf][n]);
                        Oa[mf][n] = mfma16(pal[mf], vbh[n], Oa[mf][n]);
                        Oa[mf][n] = mfma16(pah[mf], vbl[n], Oa[mf][n]);
                    }
            }
        }
        __syncthreads();
    }
    const int b = bh >> 4, hd = bh & 15;
#pragma unroll
    for (int mf = 0; mf < 2; ++mf)
#pragma unroll
        for (int r = 0; r < 4; ++r) {
            const float inv = 1.0f / lrun[mf][r];
            const int s = qw + mf * 16 + (lk << 2) + r;
#pragma unroll
            for (int n = 0; n < 4; ++n) {
                const float o = Oa[mf][n][r] * inv;
                const int d = hd * 64 + n * 16 + lrow;
                const size_t idx = ((size_t)b * SEQL + s) * DM + d;
                const u16 hi = f2bf(o);
                aoh[idx] = hi;
                aol[idx] = f2bf(o - bf2f(hi));
            }
        }
}

// ---------------------------------------------------------------------------
extern "C" void kernel_launch(void* const* d_in, const int* in_sizes, int n_in,
                              void* d_out, int out_size, void* d_ws, size_t ws_size,
                              hipStream_t stream) {
    (void)in_sizes; (void)n_in; (void)out_size; (void)ws_size;
    const float* x  = (const float*)d_in[0];
    const float* Wq = (const float*)d_in[1];
    const float* Wk = (const float*)d_in[2];
    const float* Wv = (const float*)d_in[3];
    const float* Wo = (const float*)d_in[4];
    const float* W1 = (const float*)d_in[5];
    const float* W2 = (const float*)d_in[6];
    const float* W3 = (const float*)d_in[7];
    const float* g1 = (const float*)d_in[8];
    const float* g2 = (const float*)d_in[9];
    float* out = (float*)d_out;
    char* w = (char*)d_ws;
    const size_t MB = 1024ull * 1024ull;
    // ws layout (80 MB peak): split bf16 activations.
    // Phase 1 (attn): xn 0-16, q 16-32, k 32-48, v 48-64, ao 64-80.
    // Phase 2 (ffn): xn 0-16, h 16-80 (aliases dead q/k/v/ao — safe: k_oproj,
    // the last reader of ao, completes before k_ffn1 writes h).
    u16* xnh = (u16*)(w + 0 * MB);
    u16* xnl = (u16*)(w + 8 * MB);
    u16* qh  = (u16*)(w + 16 * MB);
    u16* ql  = (u16*)(w + 24 * MB);
    u16* kh  = (u16*)(w + 32 * MB);
    u16* kl  = (u16*)(w + 40 * MB);
    u16* vh  = (u16*)(w + 48 * MB);
    u16* vl  = (u16*)(w + 56 * MB);
    u16* aoh = (u16*)(w + 64 * MB);
    u16* aol = (u16*)(w + 72 * MB);
    u16* hh  = (u16*)(w + 16 * MB);
    u16* hl  = (u16*)(w + 48 * MB);

    k_rmsnorm<<<dim3(MTOK / 4), 256, 0, stream>>>(x, g1, xnh, xnl);
    k_qkv<<<dim3(32, 24), 256, 0, stream>>>(xnh, xnl, Wq, Wk, Wv, qh, ql, kh, kl, vh, vl);
    k_attn<<<dim3(SEQL / 128, NBATCH * NH), 256, 0, stream>>>(qh, ql, kh, kl, vh, vl, aoh, aol);
    k_oproj<<<dim3(32, 8), 256, 0, stream>>>(aoh, aol, Wo, x, out);
    k_rmsnorm<<<dim3(MTOK / 4), 256, 0, stream>>>(out, g2, xnh, xnl);
    k_ffn1<<<dim3(32, 32), 256, 0, stream>>>(xnh, xnl, W1, hh, hl);
    k_ffn3<<<dim3(32, 32), 256, 0, stream>>>(xnh, xnl, W3, hh, hl);
    k_ffn2<<<dim3(32, 8), 256, 0, stream>>>(hh, hl, W2, out);
}

// Round 4
// 715.481 us; speedup vs baseline: 1.4586x; 1.4586x over previous
//
#include <hip/hip_runtime.h>
#include <hip/hip_bf16.h>

#define DM 1024
#define NH 16
#define DH 64
#define DFF 4096
#define NBATCH 2
#define SEQL 2048
#define MTOK (NBATCH*SEQL)

typedef float f32x4 __attribute__((ext_vector_type(4)));
typedef __bf16 bf16x8 __attribute__((ext_vector_type(8)));
typedef unsigned short u16;
typedef unsigned int u32;
typedef unsigned short u16x4 __attribute__((ext_vector_type(4)));
typedef unsigned short u16x8 __attribute__((ext_vector_type(8)));
typedef unsigned int u32x4 __attribute__((ext_vector_type(4)));

__device__ __forceinline__ u16 f2bf(float f) {
    u32 u = __builtin_bit_cast(u32, f);
    return (u16)((u + 0x7fffu + ((u >> 16) & 1u)) >> 16);
}
__device__ __forceinline__ float bf2f(u16 h) {
    return __builtin_bit_cast(float, (u32)h << 16);
}
__device__ __forceinline__ f32x4 mfma16(bf16x8 a, bf16x8 b, f32x4 c) {
    return __builtin_amdgcn_mfma_f32_16x16x32_bf16(a, b, c, 0, 0, 0);
}
// async global->LDS, 16B per lane. LDS dest = wave-uniform base + lane*16.
__device__ __forceinline__ void gload16(const void* g, void* l) {
    __builtin_amdgcn_global_load_lds(
        (const __attribute__((address_space(1))) unsigned int*)g,
        (__attribute__((address_space(3))) unsigned int*)l, 16, 0, 0);
}

// ---------------------------------------------------------------------------
// GEMM core: C[128x128] tile of A[M,K](bf16 hi/lo) @ B[N,K]^T.
// PRE=true: B pre-split bf16 hi/lo, staging via global_load_lds (linear LDS,
// inverse-swizzled per-lane global source — both-sides rule).
// PRE=false: B = fp32 W, split on the fly (validated fallback path).
// LDS content convention: position (row, chunk p) holds global chunk p^(row&7)
// (16B chunks), so frag reads at chunk (kc)^(row&7) are conflict-free.
// ---------------------------------------------------------------------------
template<bool PRE>
__device__ __forceinline__ void gemm_core(
    const u16* __restrict__ Ah, const u16* __restrict__ Al,
    const u16* __restrict__ Bh, const u16* __restrict__ Bl,
    const float* __restrict__ W,
    int K, int m0, int n0,
    u16* lsAh, u16* lsAl, u16* lsBh, u16* lsBl,
    f32x4 acc[4][4])
{
    const int t = threadIdx.x;
    const int lane = t & 63;
    const int wv = t >> 6;
    const int wm = ((t >> 7) & 1) * 64;
    const int wn = ((t >> 6) & 1) * 64;
    const int lrow = lane & 15;
    const int lk = lane >> 4;
    const f32x4 FZ = {0.f, 0.f, 0.f, 0.f};
#pragma unroll
    for (int i = 0; i < 4; ++i)
#pragma unroll
        for (int j = 0; j < 4; ++j) acc[i][j] = FZ;

    for (int k0 = 0; k0 < K; k0 += 64) {
        if (PRE) {
            // 16 segs of 8 rows per 128x64 tile; 4 segs per wave per array.
#pragma unroll
            for (int p = 0; p < 4; ++p) {
                const int seg = wv * 4 + p;
                const int row = seg * 8 + (lane >> 3);
                const int g = (lane & 7) ^ (row & 7);
                const size_t sa = (size_t)(m0 + row) * K + k0 + g * 8;
                const size_t sb = (size_t)(n0 + row) * K + k0 + g * 8;
                gload16(Ah + sa, lsAh + seg * 512);
                gload16(Al + sa, lsAl + seg * 512);
                gload16(Bh + sb, lsBh + seg * 512);
                gload16(Bl + sb, lsBl + seg * 512);
            }
        } else {
#pragma unroll
            for (int j = 0; j < 4; ++j) {
                const int row = (t >> 3) + j * 32;
                const int chk = t & 7;
                const size_t src = (size_t)(m0 + row) * K + k0 + chk * 8;
                const int di = row * 64 + ((chk ^ (row & 7)) << 3);
                *reinterpret_cast<u16x8*>(&lsAh[di]) = *reinterpret_cast<const u16x8*>(&Ah[src]);
                *reinterpret_cast<u16x8*>(&lsAl[di]) = *reinterpret_cast<const u16x8*>(&Al[src]);
            }
#pragma unroll
            for (int j = 0; j < 8; ++j) {
                const int id = t + j * 256;
                const int row = id >> 4;
                const int f4 = id & 15;
                const f32x4 wv4 = *reinterpret_cast<const f32x4*>(&W[(size_t)(n0 + row) * K + k0 + f4 * 4]);
                u16x4 hh, ll;
#pragma unroll
                for (int e = 0; e < 4; ++e) {
                    const u16 hi = f2bf(wv4[e]);
                    hh[e] = hi;
                    ll[e] = f2bf(wv4[e] - bf2f(hi));
                }
                const int kc = f4 * 4;
                const int di = row * 64 + ((((kc >> 3) ^ (row & 7))) << 3) + (kc & 7);
                *reinterpret_cast<u16x4*>(&lsBh[di]) = hh;
                *reinterpret_cast<u16x4*>(&lsBl[di]) = ll;
            }
        }
        __syncthreads();
#pragma unroll
        for (int ks = 0; ks < 2; ++ks) {
            bf16x8 ah[4], al[4], bh[4], bl[4];
#pragma unroll
            for (int i = 0; i < 4; ++i) {
                const int ra = wm + i * 16 + lrow;
                const int ia = ra * 64 + ((((lk + ks * 4) ^ (ra & 7))) << 3);
                ah[i] = *reinterpret_cast<const bf16x8*>(&lsAh[ia]);
                al[i] = *reinterpret_cast<const bf16x8*>(&lsAl[ia]);
                const int rb = wn + i * 16 + lrow;
                const int ib = rb * 64 + ((((lk + ks * 4) ^ (rb & 7))) << 3);
                bh[i] = *reinterpret_cast<const bf16x8*>(&lsBh[ib]);
                bl[i] = *reinterpret_cast<const bf16x8*>(&lsBl[ib]);
            }
#pragma unroll
            for (int i = 0; i < 4; ++i)
#pragma unroll
                for (int j = 0; j < 4; ++j) {
                    acc[i][j] = mfma16(ah[i], bh[j], acc[i][j]);
                    acc[i][j] = mfma16(al[i], bh[j], acc[i][j]);
                    acc[i][j] = mfma16(ah[i], bl[j], acc[i][j]);
                }
        }
        __syncthreads();
    }
}

// C/D frag mapping (HW-verified m89): col = lane&15, row = (lane>>4)*4 + r
template <class F>
__device__ __forceinline__ void epilogue(const f32x4 acc[4][4], int m0, int n0, F f) {
    const int lane = threadIdx.x & 63;
    const int wm = ((threadIdx.x >> 7) & 1) * 64;
    const int wn = ((threadIdx.x >> 6) & 1) * 64;
#pragma unroll
    for (int i = 0; i < 4; ++i)
#pragma unroll
        for (int j = 0; j < 4; ++j)
#pragma unroll
            for (int r = 0; r < 4; ++r) {
                const int m = m0 + wm + i * 16 + ((lane >> 4) << 2) + r;
                const int o = n0 + wn + j * 16 + (lane & 15);
                f(m, o, acc[i][j][r]);
            }
}

// ---------------------------------------------------------------------------
__global__ __launch_bounds__(256) void k_splitw(
    const float* __restrict__ src, u16* __restrict__ dh, u16* __restrict__ dl, int n)
{
    const int i = (blockIdx.x * 256 + threadIdx.x) * 8;
    if (i + 8 > n) return;
    const f32x4 a = *reinterpret_cast<const f32x4*>(src + i);
    const f32x4 b = *reinterpret_cast<const f32x4*>(src + i + 4);
    u16x8 hh, ll;
#pragma unroll
    for (int e = 0; e < 4; ++e) {
        const u16 h0 = f2bf(a[e]);
        hh[e] = h0; ll[e] = f2bf(a[e] - bf2f(h0));
        const u16 h1 = f2bf(b[e]);
        hh[4 + e] = h1; ll[4 + e] = f2bf(b[e] - bf2f(h1));
    }
    *reinterpret_cast<u16x8*>(dh + i) = hh;
    *reinterpret_cast<u16x8*>(dl + i) = ll;
}

__global__ __launch_bounds__(256) void k_rmsnorm(
    const float* __restrict__ x, const float* __restrict__ g,
    u16* __restrict__ oh, u16* __restrict__ ol)
{
    const int row = blockIdx.x * 4 + (threadIdx.x >> 6);
    const int lane = threadIdx.x & 63;
    const float* xr = x + (size_t)row * DM;
    f32x4 v[4];
    float ss = 0.f;
#pragma unroll
    for (int j = 0; j < 4; ++j) {
        v[j] = *reinterpret_cast<const f32x4*>(&xr[(lane + j * 64) * 4]);
        ss += v[j][0] * v[j][0] + v[j][1] * v[j][1] + v[j][2] * v[j][2] + v[j][3] * v[j][3];
    }
#pragma unroll
    for (int off = 32; off > 0; off >>= 1) ss += __shfl_xor(ss, off, 64);
    const float sc = 1.0f / sqrtf(ss * (1.0f / (float)DM) + 1e-5f);
#pragma unroll
    for (int j = 0; j < 4; ++j) {
        const int c0 = (lane + j * 64) * 4;
        const f32x4 gv = *reinterpret_cast<const f32x4*>(&g[c0]);
        u16x4 hh, ll;
#pragma unroll
        for (int e = 0; e < 4; ++e) {
            const float y = v[j][e] * sc * gv[e];
            const u16 hi = f2bf(y);
            hh[e] = hi;
            ll[e] = f2bf(y - bf2f(hi));
        }
        *reinterpret_cast<u16x4*>(&oh[(size_t)row * DM + c0]) = hh;
        *reinterpret_cast<u16x4*>(&ol[(size_t)row * DM + c0]) = ll;
    }
}

// QKV: grid (32, 24). q,k in [B,H,S,dh]; v stored TRANSPOSED [B,H,dh,S].
template<bool PRE>
__global__ __launch_bounds__(256) void k_qkv(
    const u16* __restrict__ Ah, const u16* __restrict__ Al,
    const float* __restrict__ Wq, const float* __restrict__ Wk, const float* __restrict__ Wv,
    const u16* __restrict__ swqh, const u16* __restrict__ swql,
    const u16* __restrict__ swkh, const u16* __restrict__ swkl,
    const u16* __restrict__ swvh, const u16* __restrict__ swvl,
    u16* __restrict__ qh, u16* __restrict__ ql, u16* __restrict__ kh, u16* __restrict__ kl,
    u16* __restrict__ vth, u16* __restrict__ vtl)
{
    __shared__ __align__(16) u16 lsAh[128 * 64], lsAl[128 * 64], lsBh[128 * 64], lsBl[128 * 64];
    const int m0 = blockIdx.x * 128;
    const int ng = blockIdx.y * 128;
    const int proj = ng >> 10;
    const int n0 = ng & 1023;
    const float* W = (proj == 0) ? Wq : ((proj == 1) ? Wk : Wv);
    const u16* Bh = (proj == 0) ? swqh : ((proj == 1) ? swkh : swvh);
    const u16* Bl = (proj == 0) ? swql : ((proj == 1) ? swkl : swvl);
    f32x4 acc[4][4];
    gemm_core<PRE>(Ah, Al, Bh, Bl, W, DM, m0, n0, lsAh, lsAl, lsBh, lsBl, acc);
    if (proj < 2) {
        u16* oph = (proj == 0) ? qh : kh;
        u16* opl = (proj == 0) ? ql : kl;
        epilogue(acc, m0, n0, [&](int m, int o, float val) {
            const int b = m >> 11, s = m & (SEQL - 1);
            const int hd = o >> 6, d = o & 63;
            const size_t idx = (((size_t)b * NH + hd) * SEQL + s) * DH + d;
            const u16 hi = f2bf(val);
            oph[idx] = hi;
            opl[idx] = f2bf(val - bf2f(hi));
        });
    } else {
        epilogue(acc, m0, n0, [&](int m, int o, float val) {
            const int b = m >> 11, s = m & (SEQL - 1);
            const int hd = o >> 6, d = o & 63;
            const size_t idx = (((size_t)b * NH + hd) * DH + d) * SEQL + s;
            const u16 hi = f2bf(val);
            vth[idx] = hi;
            vtl[idx] = f2bf(val - bf2f(hi));
        });
    }
}

template<bool PRE>
__global__ __launch_bounds__(256) void k_oproj(
    const u16* __restrict__ Ah, const u16* __restrict__ Al,
    const float* __restrict__ Wo, const u16* __restrict__ Bh, const u16* __restrict__ Bl,
    const float* __restrict__ xres, float* __restrict__ out)
{
    __shared__ __align__(16) u16 lsAh[128 * 64], lsAl[128 * 64], lsBh[128 * 64], lsBl[128 * 64];
    const int m0 = blockIdx.x * 128;
    const int n0 = blockIdx.y * 128;
    f32x4 acc[4][4];
    gemm_core<PRE>(Ah, Al, Bh, Bl, Wo, DM, m0, n0, lsAh, lsAl, lsBh, lsBl, acc);
    epilogue(acc, m0, n0, [&](int m, int o, float val) {
        const size_t idx = (size_t)m * DM + o;
        out[idx] = xres[idx] + val;
    });
}

template<bool PRE>
__global__ __launch_bounds__(256) void k_ffn1(
    const u16* __restrict__ Ah, const u16* __restrict__ Al,
    const float* __restrict__ W1, const u16* __restrict__ Bh, const u16* __restrict__ Bl,
    u16* __restrict__ hh, u16* __restrict__ hl)
{
    __shared__ __align__(16) u16 lsAh[128 * 64], lsAl[128 * 64], lsBh[128 * 64], lsBl[128 * 64];
    const int m0 = blockIdx.x * 128;
    const int n0 = blockIdx.y * 128;
    f32x4 acc[4][4];
    gemm_core<PRE>(Ah, Al, Bh, Bl, W1, DM, m0, n0, lsAh, lsAl, lsBh, lsBl, acc);
    epilogue(acc, m0, n0, [&](int m, int o, float val) {
        const size_t idx = (size_t)m * DFF + o;
        const u16 hi = f2bf(val);
        hh[idx] = hi;
        hl[idx] = f2bf(val - bf2f(hi));
    });
}

template<bool PRE>
__global__ __launch_bounds__(256) void k_ffn3(
    const u16* __restrict__ Ah, const u16* __restrict__ Al,
    const float* __restrict__ W3, const u16* __restrict__ Bh, const u16* __restrict__ Bl,
    u16* __restrict__ hh, u16* __restrict__ hl)
{
    __shared__ __align__(16) u16 lsAh[128 * 64], lsAl[128 * 64], lsBh[128 * 64], lsBl[128 * 64];
    const int m0 = blockIdx.x * 128;
    const int n0 = blockIdx.y * 128;
    f32x4 acc[4][4];
    gemm_core<PRE>(Ah, Al, Bh, Bl, W3, DM, m0, n0, lsAh, lsAl, lsBh, lsBl, acc);
    epilogue(acc, m0, n0, [&](int m, int o, float val) {
        const size_t idx = (size_t)m * DFF + o;
        const float h1 = bf2f(hh[idx]) + bf2f(hl[idx]);
        const float sg = 1.0f / (1.0f + expf(-h1));
        const float hv = h1 * sg * val;
        const u16 hi = f2bf(hv);
        hh[idx] = hi;
        hl[idx] = f2bf(hv - bf2f(hi));
    });
}

template<bool PRE>
__global__ __launch_bounds__(256) void k_ffn2(
    const u16* __restrict__ Ah, const u16* __restrict__ Al,
    const float* __restrict__ W2, const u16* __restrict__ Bh, const u16* __restrict__ Bl,
    float* __restrict__ out)
{
    __shared__ __align__(16) u16 lsAh[128 * 64], lsAl[128 * 64], lsBh[128 * 64], lsBl[128 * 64];
    const int m0 = blockIdx.x * 128;
    const int n0 = blockIdx.y * 128;
    f32x4 acc[4][4];
    gemm_core<PRE>(Ah, Al, Bh, Bl, W2, DFF, m0, n0, lsAh, lsAl, lsBh, lsBl, acc);
    epilogue(acc, m0, n0, [&](int m, int o, float val) {
        const size_t idx = (size_t)m * DM + o;
        out[idx] = out[idx] + val;
    });
}

// ---------------------------------------------------------------------------
// Flash attention v2. grid (16, 32): x = causal pair index (q-tiles pr and
// 31-pr, 64 rows each => every block does exactly 33 KV-tile iterations).
// 4 waves, each owns 16 q-rows. K [kv][d] and V^T [d][kv] staged via
// global_load_lds (pre-swizzled source), double-buffered with prefetch.
// ---------------------------------------------------------------------------
__global__ __launch_bounds__(256) void k_attn(
    const u16* __restrict__ gqh, const u16* __restrict__ gql,
    const u16* __restrict__ gkh, const u16* __restrict__ gkl,
    const u16* __restrict__ gvth, const u16* __restrict__ gvtl,
    u16* __restrict__ aoh, u16* __restrict__ aol)
{
    __shared__ __align__(16) u16 sKh[2][4096], sKl[2][4096], sVh[2][4096], sVl[2][4096];
    __shared__ __align__(16) u32 Pw[4][16 * 64];
    const int t = threadIdx.x, lane = t & 63, wid = t >> 6;
    const int lrow = lane & 15, lk = lane >> 4;
    const int bh = blockIdx.y;
    const int pr = blockIdx.x;
    const size_t base = (size_t)bh * SEQL * DH;
    const f32x4 FZ = {0.f, 0.f, 0.f, 0.f};
    const int b = bh >> 4, hd = bh & 15;

    auto stage = [&](int buf, int kvt) {
        const int kv0 = kvt << 6;
#pragma unroll
        for (int p = 0; p < 2; ++p) {
            const int seg = wid * 2 + p;            // 0..7, 8 rows each
            const int row = seg * 8 + (lane >> 3);
            const int g = (lane & 7) ^ (row & 7);
            const size_t sk = base + (size_t)(kv0 + row) * DH + g * 8;
            const size_t sv = base + (size_t)row * SEQL + kv0 + g * 8;
            gload16(gkh + sk, &sKh[buf][seg * 512]);
            gload16(gkl + sk, &sKl[buf][seg * 512]);
            gload16(gvth + sv, &sVh[buf][seg * 512]);
            gload16(gvtl + sv, &sVl[buf][seg * 512]);
        }
    };

    for (int hf = 0; hf < 2; ++hf) {
        const int qt = hf ? (31 - pr) : pr;
        const int qw = qt * 64 + wid * 16;
        bf16x8 Qh[2], Ql[2];
#pragma unroll
        for (int ks = 0; ks < 2; ++ks) {
            const size_t off = base + (size_t)(qw + lrow) * DH + ks * 32 + lk * 8;
            Qh[ks] = *reinterpret_cast<const bf16x8*>(&gqh[off]);
            Ql[ks] = *reinterpret_cast<const bf16x8*>(&gql[off]);
        }
        float mr[4], lr[4];
        f32x4 Oa[4];
#pragma unroll
        for (int r = 0; r < 4; ++r) { mr[r] = -1.0e30f; lr[r] = 0.f; }
#pragma unroll
        for (int n = 0; n < 4; ++n) Oa[n] = FZ;

        const int ntile = qt + 1;
        stage(0, 0);
        __syncthreads();
        int buf = 0;
        for (int kvt = 0; kvt < ntile; ++kvt) {
            if (kvt + 1 < ntile) stage(buf ^ 1, kvt + 1);
            const int kv0 = kvt << 6;
            // ---- QK^T ----
            f32x4 S[4];
#pragma unroll
            for (int nf = 0; nf < 4; ++nf) S[nf] = FZ;
#pragma unroll
            for (int ks = 0; ks < 2; ++ks) {
                bf16x8 kbh[4], kbl[4];
#pragma unroll
                for (int nf = 0; nf < 4; ++nf) {
                    const int row = nf * 16 + lrow;
                    const int idx = row * 64 + (((lk + ks * 4) ^ (row & 7)) << 3);
                    kbh[nf] = *reinterpret_cast<const bf16x8*>(&sKh[buf][idx]);
                    kbl[nf] = *reinterpret_cast<const bf16x8*>(&sKl[buf][idx]);
                }
#pragma unroll
                for (int nf = 0; nf < 4; ++nf) {
                    S[nf] = mfma16(Qh[ks], kbh[nf], S[nf]);
                    S[nf] = mfma16(Ql[ks], kbh[nf], S[nf]);
                    S[nf] = mfma16(Qh[ks], kbl[nf], S[nf]);
                }
            }
            // ---- online softmax (scale 1/8) ----
#pragma unroll
            for (int r = 0; r < 4; ++r) {
                const int qrow = qw + (lk << 2) + r;
                float rmx = -3.0e38f;
#pragma unroll
                for (int nf = 0; nf < 4; ++nf) {
                    const int col = kv0 + nf * 16 + lrow;
                    const float tv = (col <= qrow) ? S[nf][r] * 0.125f : -3.0e38f;
                    S[nf][r] = tv;
                    rmx = fmaxf(rmx, tv);
                }
#pragma unroll
                for (int off = 8; off > 0; off >>= 1) rmx = fmaxf(rmx, __shfl_xor(rmx, off, 16));
                const float mnew = fmaxf(mr[r], rmx);
                const float alpha = exp2f((mr[r] - mnew) * 1.44269504f);
                mr[r] = mnew;
                float rsum = 0.f;
#pragma unroll
                for (int nf = 0; nf < 4; ++nf) {
                    const float p = exp2f((S[nf][r] - mnew) * 1.44269504f);
                    S[nf][r] = p;
                    rsum += p;
                }
#pragma unroll
                for (int off = 8; off > 0; off >>= 1) rsum += __shfl_xor(rsum, off, 16);
                lr[r] = lr[r] * alpha + rsum;
#pragma unroll
                for (int n = 0; n < 4; ++n) Oa[n][r] *= alpha;
                const int prow = (lk << 2) + r;
#pragma unroll
                for (int nf = 0; nf < 4; ++nf) {
                    const float p = S[nf][r];
                    const u16 phi = f2bf(p);
                    const u16 plo = f2bf(p - bf2f(phi));
                    const int pcol = nf * 16 + lrow;
                    Pw[wid][prow * 64 + ((((pcol >> 3) ^ (prow & 7))) << 3) + (pcol & 7)] =
                        (u32)phi | ((u32)plo << 16);
                }
            }
            asm volatile("s_waitcnt lgkmcnt(0)" ::: "memory");
            // ---- P @ V (A-frag from Pw, B-frag from V^T tile) ----
#pragma unroll
            for (int ks = 0; ks < 2; ++ks) {
                const int row = lrow;
                const int c = (lk + ks * 4) ^ (row & 7);
                const u32* pp = &Pw[wid][row * 64 + (c << 3)];
                const u32x4 w0 = *reinterpret_cast<const u32x4*>(pp);
                const u32x4 w1 = *reinterpret_cast<const u32x4*>(pp + 4);
                union { u16 s[8]; bf16x8 v; } uh, ul;
#pragma unroll
                for (int e = 0; e < 4; ++e) {
                    uh.s[e] = (u16)(w0[e] & 0xffffu); ul.s[e] = (u16)(w0[e] >> 16);
                    uh.s[e + 4] = (u16)(w1[e] & 0xffffu); ul.s[e + 4] = (u16)(w1[e] >> 16);
                }
                bf16x8 vbh[4], vbl[4];
#pragma unroll
                for (int n = 0; n < 4; ++n) {
                    const int vr = n * 16 + lrow;
                    const int idx = vr * 64 + (((lk + ks * 4) ^ (vr & 7)) << 3);
                    vbh[n] = *reinterpret_cast<const bf16x8*>(&sVh[buf][idx]);
                    vbl[n] = *reinterpret_cast<const bf16x8*>(&sVl[buf][idx]);
                }
#pragma unroll
                for (int n = 0; n < 4; ++n) {
                    Oa[n] = mfma16(uh.v, vbh[n], Oa[n]);
                    Oa[n] = mfma16(ul.v, vbh[n], Oa[n]);
                    Oa[n] = mfma16(uh.v, vbl[n], Oa[n]);
                }
            }
            __syncthreads();
            buf ^= 1;
        }
        // ---- writeout ----
#pragma unroll
        for (int r = 0; r < 4; ++r) {
            const float inv = 1.0f / lr[r];
            const int s = qw + (lk << 2) + r;
#pragma unroll
            for (int n = 0; n < 4; ++n) {
                const float o = Oa[n][r] * inv;
                const int d = hd * 64 + n * 16 + lrow;
                const size_t idx = ((size_t)b * SEQL + s) * DM + d;
                const u16 hi = f2bf(o);
                aoh[idx] = hi;
                aol[idx] = f2bf(o - bf2f(hi));
            }
        }
    }
}

// ---------------------------------------------------------------------------
extern "C" void kernel_launch(void* const* d_in, const int* in_sizes, int n_in,
                              void* d_out, int out_size, void* d_ws, size_t ws_size,
                              hipStream_t stream) {
    (void)in_sizes; (void)n_in; (void)out_size;
    const float* x  = (const float*)d_in[0];
    const float* Wq = (const float*)d_in[1];
    const float* Wk = (const float*)d_in[2];
    const float* Wv = (const float*)d_in[3];
    const float* Wo = (const float*)d_in[4];
    const float* W1 = (const float*)d_in[5];
    const float* W2 = (const float*)d_in[6];
    const float* W3 = (const float*)d_in[7];
    const float* g1 = (const float*)d_in[8];
    const float* g2 = (const float*)d_in[9];
    float* out = (float*)d_out;
    char* w = (char*)d_ws;
    const size_t MB = 1024ull * 1024ull;
    // Activations (80 MiB):
    u16* xnh = (u16*)(w + 0 * MB);
    u16* xnl = (u16*)(w + 8 * MB);
    u16* qh  = (u16*)(w + 16 * MB);
    u16* ql  = (u16*)(w + 24 * MB);
    u16* kh  = (u16*)(w + 32 * MB);
    u16* kl  = (u16*)(w + 40 * MB);
    u16* vth = (u16*)(w + 48 * MB);
    u16* vtl = (u16*)(w + 56 * MB);
    u16* aoh = (u16*)(w + 64 * MB);
    u16* aol = (u16*)(w + 72 * MB);
    u16* hh  = (u16*)(w + 16 * MB);   // aliases q..v after oproj
    u16* hl  = (u16*)(w + 48 * MB);
    // Pre-split weights (64 MiB at +80): plan A only.
    const bool pre = ws_size >= (144ull << 20);
    u16* wsp = (u16*)(w + 80 * MB);
    u16* wqh = wsp;                  u16* wql = wqh + (1u << 20);
    u16* wkh = wql + (1u << 20);     u16* wkl = wkh + (1u << 20);
    u16* wvh = wkl + (1u << 20);     u16* wvl = wvh + (1u << 20);
    u16* woh = wvl + (1u << 20);     u16* wol = woh + (1u << 20);
    u16* w1h = wol + (1u << 20);     u16* w1l = w1h + (4u << 20);
    u16* w2h = w1l + (4u << 20);     u16* w2l = w2h + (4u << 20);
    u16* w3h = w2l + (4u << 20);     u16* w3l = w3h + (4u << 20);

    if (pre) {
        k_splitw<<<512, 256, 0, stream>>>(Wq, wqh, wql, 1 << 20);
        k_splitw<<<512, 256, 0, stream>>>(Wk, wkh, wkl, 1 << 20);
        k_splitw<<<512, 256, 0, stream>>>(Wv, wvh, wvl, 1 << 20);
        k_splitw<<<512, 256, 0, stream>>>(Wo, woh, wol, 1 << 20);
        k_splitw<<<2048, 256, 0, stream>>>(W1, w1h, w1l, 4 << 20);
        k_splitw<<<2048, 256, 0, stream>>>(W2, w2h, w2l, 4 << 20);
        k_splitw<<<2048, 256, 0, stream>>>(W3, w3h, w3l, 4 << 20);
    }
    k_rmsnorm<<<dim3(MTOK / 4), 256, 0, stream>>>(x, g1, xnh, xnl);
    if (pre) {
        k_qkv<true><<<dim3(32, 24), 256, 0, stream>>>(xnh, xnl, Wq, Wk, Wv,
            wqh, wql, wkh, wkl, wvh, wvl, qh, ql, kh, kl, vth, vtl);
        k_attn<<<dim3(16, 32), 256, 0, stream>>>(qh, ql, kh, kl, vth, vtl, aoh, aol);
        k_oproj<true><<<dim3(32, 8), 256, 0, stream>>>(aoh, aol, Wo, woh, wol, x, out);
        k_rmsnorm<<<dim3(MTOK / 4), 256, 0, stream>>>(out, g2, xnh, xnl);
        k_ffn1<true><<<dim3(32, 32), 256, 0, stream>>>(xnh, xnl, W1, w1h, w1l, hh, hl);
        k_ffn3<true><<<dim3(32, 32), 256, 0, stream>>>(xnh, xnl, W3, w3h, w3l, hh, hl);
        k_ffn2<true><<<dim3(32, 8), 256, 0, stream>>>(hh, hl, W2, w2h, w2l, out);
    } else {
        k_qkv<false><<<dim3(32, 24), 256, 0, stream>>>(xnh, xnl, Wq, Wk, Wv,
            nullptr, nullptr, nullptr, nullptr, nullptr, nullptr, qh, ql, kh, kl, vth, vtl);
        k_attn<<<dim3(16, 32), 256, 0, stream>>>(qh, ql, kh, kl, vth, vtl, aoh, aol);
        k_oproj<false><<<dim3(32, 8), 256, 0, stream>>>(aoh, aol, Wo, nullptr, nullptr, x, out);
        k_rmsnorm<<<dim3(MTOK / 4), 256, 0, stream>>>(out, g2, xnh, xnl);
        k_ffn1<false><<<dim3(32, 32), 256, 0, stream>>>(xnh, xnl, W1, nullptr, nullptr, hh, hl);
        k_ffn3<false><<<dim3(32, 32), 256, 0, stream>>>(xnh, xnl, W3, nullptr, nullptr, hh, hl);
        k_ffn2<false><<<dim3(32, 8), 256, 0, stream>>>(hh, hl, W2, nullptr, nullptr, out);
    }
}